// Round 9
// baseline (419.095 us; speedup 1.0000x reference)
//
#include <hip/hip_runtime.h>

// NNMF fused: B=8192, NIN=3072, NOUT=512, 5 iterations.
// R15: R14 + w2v reload-one-slot-ahead (zero-register software pipeline).
//  R14 (240.6 us): busy sum ~2090 cy of 4820 cy slot; residual ~2700 cy ~=
//  W L2 stream (2340 cy/CU for 128 KB) + barrier sync -> W stream still
//  serializes. Cause is TIMING: w2v for slot s issues at slot-s top, is
//  consumed ~1600 cy later, but the channel needs ~2340 cy. Fix costs zero
//  registers: reload w2v[nt] for s+1 right after its last MFMA use in
//  Phase B of slot s (the proven w1buf pattern) -> every W2 load gets
//  ~3000+ cy of cover. w2v persists across slots/iterations (preloaded
//  once). WAR on the same registers pins the issue point. Single change
//  vs R14; numerics identical.

#define NIN 3072
#define NOUT 512

using f32x4 = __attribute__((ext_vector_type(4))) float;
using i32x8 = __attribute__((ext_vector_type(8))) int;

union frag32 { i32x8 v; uint4 q[2]; };

#define MFMA128(A, B, C) \
    __builtin_amdgcn_mfma_scale_f32_16x16x128_f8f6f4( \
        (A), (B), (C), 0, 0, 0, (int)0x7f7f7f7f, 0, (int)0x7f7f7f7f)

__device__ __forceinline__ unsigned short f2bf(float f) {
    unsigned int u = __builtin_bit_cast(unsigned int, f);
    return (unsigned short)((u + 0x7fffu + ((u >> 16) & 1u)) >> 16);  // RNE
}
__device__ __forceinline__ float bf2f(unsigned short s) {
    unsigned int u = ((unsigned int)s) << 16;
    return __builtin_bit_cast(float, u);
}

// LDS-only barrier: cross-wave deps in the slot loop are LDS-only; global
// prefetches stay in flight (consumed by issuing wave, compiler inserts vmcnt).
#define LDS_BARRIER() do {                                   \
    asm volatile("s_waitcnt lgkmcnt(0)" ::: "memory");       \
    __builtin_amdgcn_s_barrier();                            \
    asm volatile("" ::: "memory");                           \
} while (0)

// ---------------------------------------------------------------------------
// prep_all: one launch, 8672 blocks x 256 threads.
//   blocks [0,8192)     : per-row x normalize (x16 pre-scale) -> bf16 X2
//   blocks [8192,8576)  : W -> W2 / W1 (fp8 e4m3, x4096, K=128 frag layout)
//   blocks [8576,8672)  : d0inv[k] = 1/(sum_n h0[n]*W[n][k] + 1e-20)
// K=128 fragment layouts (lane l holds 32 contiguous contraction elements,
// k = (l>>4)*32 + j):
//   W2 (Phase B B-op): addr = ((s*32 + w*4 + nt)*64 + l)*32 + j   (LINEAR)
//     element: n = w*64 + nt*16 + (l&15), k = s*128 + (l>>4)*32 + j
//   W1 (Phase A B-op): addr = (((s*8 + w)*4 + c)*64 + l)*32 + j   (LINEAR)
//     element: kout = s*128 + w*16 + (l&15), n = c*128 + (l>>4)*32 + j
// ---------------------------------------------------------------------------
__global__ void prep_all(const float* __restrict__ x,
                         const float* __restrict__ W,
                         const float* __restrict__ h_init,
                         unsigned short* __restrict__ X2,
                         unsigned char* __restrict__ W1,
                         unsigned char* __restrict__ W2,
                         float* __restrict__ d0inv) {
    __shared__ float wsum[4];
    __shared__ float dred[8][32];
    const int bb = blockIdx.x;
    const int t  = threadIdx.x;

    if (bb < 8192) {
        // ---- x row normalize -> bf16, pre-scaled x16 (exact: power of 2)
        const int b = bb;
        const float4* r4 = reinterpret_cast<const float4*>(x + (size_t)b * NIN);
        float s = 0.f;
        float4 v0 = r4[t], v1 = r4[t + 256], v2 = r4[t + 512];
        s = v0.x + v0.y + v0.z + v0.w + v1.x + v1.y + v1.z + v1.w + v2.x + v2.y + v2.z + v2.w;
        #pragma unroll
        for (int off = 32; off > 0; off >>= 1) s += __shfl_down(s, off, 64);
        int w = t >> 6, l = t & 63;
        if (l == 0) wsum[w] = s;
        __syncthreads();
        float inv = 16.0f / (wsum[0] + wsum[1] + wsum[2] + wsum[3] + 1e-20f);
        unsigned short* orow = X2 + (size_t)b * NIN;
        #pragma unroll
        for (int c = 0; c < 3; ++c) {
            float4 v = (c == 0) ? v0 : (c == 1) ? v1 : v2;
            ushort4 o;
            o.x = f2bf(v.x * inv); o.y = f2bf(v.y * inv);
            o.z = f2bf(v.z * inv); o.w = f2bf(v.w * inv);
            *reinterpret_cast<ushort4*>(orow + (t + c * 256) * 4) = o;
        }
    } else if (bb < 8192 + 384) {
        // ---- W quantization, K=128 frag layouts (32 B per thread)
        int tt = (bb - 8192) * 256 + t;       // 0 .. 98303
        unsigned int words[8];
        if (tt < 49152) {
            // W2: g = s*32 + w*4 + nt  (linear store)
            int l = tt & 63, g = tt >> 6;
            int s = g >> 5, rem = g & 31, w = rem >> 2, nt = rem & 3;
            int n = w * 64 + nt * 16 + (l & 15);
            int kbase = s * 128 + ((l >> 4) << 5);
            const float* src = W + (size_t)n * NIN + kbase;
            #pragma unroll
            for (int q = 0; q < 8; ++q) {
                float v0 = src[q * 4 + 0] * 4096.0f, v1 = src[q * 4 + 1] * 4096.0f;
                float v2 = src[q * 4 + 2] * 4096.0f, v3 = src[q * 4 + 3] * 4096.0f;
                int pk = __builtin_amdgcn_cvt_pk_fp8_f32(v0, v1, 0, false);
                pk     = __builtin_amdgcn_cvt_pk_fp8_f32(v2, v3, pk, true);
                words[q] = (unsigned int)pk;
            }
            uint4* dst = reinterpret_cast<uint4*>(W2 + (size_t)tt * 32);
            dst[0] = *reinterpret_cast<uint4*>(&words[0]);
            dst[1] = *reinterpret_cast<uint4*>(&words[4]);
        } else {
            // W1: g = (s*8 + w)*4 + c  (linear store)
            int u = tt - 49152;
            int l = u & 63, g = u >> 6;
            int c = g & 3, sw = g >> 2;
            int w = sw & 7, s = sw >> 3;
            int kout = s * 128 + w * 16 + (l & 15);
            int nbase = c * 128 + ((l >> 4) << 5);
            #pragma unroll
            for (int q = 0; q < 8; ++q) {
                float v0 = W[(size_t)(nbase + q * 4 + 0) * NIN + kout] * 4096.0f;
                float v1 = W[(size_t)(nbase + q * 4 + 1) * NIN + kout] * 4096.0f;
                float v2 = W[(size_t)(nbase + q * 4 + 2) * NIN + kout] * 4096.0f;
                float v3 = W[(size_t)(nbase + q * 4 + 3) * NIN + kout] * 4096.0f;
                int pk = __builtin_amdgcn_cvt_pk_fp8_f32(v0, v1, 0, false);
                pk     = __builtin_amdgcn_cvt_pk_fp8_f32(v2, v3, pk, true);
                words[q] = (unsigned int)pk;
            }
            uint4* dst = reinterpret_cast<uint4*>(W1 + (size_t)u * 32);
            dst[0] = *reinterpret_cast<uint4*>(&words[0]);
            dst[1] = *reinterpret_cast<uint4*>(&words[4]);
        }
    } else {
        // ---- d0inv: block owns 32 k-cols; thread (kid = t&31, nsub = t>>5)
        int kb = bb - 8576;                   // 0..95
        int kid = t & 31, nsub = t >> 5;      // 8 n-chunks of 64
        int k = kb * 32 + kid;
        int n0 = nsub * 64;
        float s = 0.f;
        const float* p = W + (size_t)n0 * NIN + k;
        #pragma unroll 8
        for (int n = 0; n < 64; ++n) s += h_init[n0 + n] * p[(size_t)n * NIN];
        dred[nsub][kid] = s;
        __syncthreads();
        if (t < 32) {
            float sm = 1e-20f;
            #pragma unroll
            for (int j = 0; j < 8; ++j) sm += dred[j][t];
            d0inv[kb * 32 + t] = 1.0f / sm;
        }
    }
}

// ---------------------------------------------------------------------------
// Main kernel. 256 blocks x 512 threads (8 waves), 32 rows/block, 1 block/CU.
// R14 structure; all W/x streams load one slot ahead into the same registers.
// ---------------------------------------------------------------------------
__global__ __launch_bounds__(512, 1) void nnmf_main(
    const unsigned short* __restrict__ X2,
    const unsigned char* __restrict__ W1,
    const unsigned char* __restrict__ W2,
    const float* __restrict__ d0inv,
    const float* __restrict__ h_init,
    float* __restrict__ out)
{
    __shared__ unsigned char  h8_lds[32 * 528];   // 16.9 KB (fp8 h, x256)
    __shared__ float          h32_lds[32 * 516];  // 66.0 KB (fp32 h master)
    __shared__ unsigned short x_lds[32 * 136];    //  8.7 KB
    __shared__ unsigned char  r8_lds[32 * 144];   //  4.6 KB (fp8 r, stride 144B)
    __shared__ float red[8][32];
    // total ~97.3 KB

    const int tid = threadIdx.x;
    const int w  = tid >> 6;        // wave 0..7
    const int l  = tid & 63;
    const int lo = l & 15;
    const int hi = l >> 4;          // 0..3
    const int b0 = blockIdx.x * 32;

    // fp32 h master init (LDS; each (row,col) owned by one thread at boundary)
    for (int idx = tid; idx < 32 * 512; idx += 512) {
        int r = idx >> 9, c = idx & 511;
        h32_lds[r * 516 + c] = h_init[c];
    }

    // x staging: thread -> (row, 16B chunk)
    const int xrow = tid >> 4, xcc = tid & 15;
    const uint4* xg = reinterpret_cast<const uint4*>(X2 + (size_t)(b0 + xrow) * NIN + xcc * 8);
    unsigned short* xdst = &x_lds[xrow * 136 + xcc * 8];

    // W pointers (fp8, K=128 frag layouts; 32-B aligned per lane)
    const unsigned char* w1base = W1 + (size_t)w * 8192 + (size_t)l * 32;   // +s*65536 +c*2048
    const unsigned char* w2base = W2 + (size_t)w * 8192 + (size_t)l * 32;   // +s*65536 +nt*2048

    // prime pipeline: x[0] -> LDS, x[1] -> reg; preload w2v = W2[0]
    *reinterpret_cast<uint4*>(xdst) = xg[0];
    uint4 xnext = xg[16];
    frag32 w1buf[4];                // Phase A B-frags (valid from it0 s==23 on)
    frag32 w2v[4];                  // Phase B B-frags, persistent, 1-slot-ahead
    #pragma unroll
    for (int nt = 0; nt < 4; ++nt) {
        const uint4* p = reinterpret_cast<const uint4*>(w2base + nt * 2048);
        w2v[nt].q[0] = p[0];
        w2v[nt].q[1] = p[1];
    }
    __syncthreads();

    const float DSCL = 9.5367431640625e-07f;  // 2^-20: undo h x256 * W1 x4096
    const float TS   = 1.0f / 65536.0f;       // undo W2 x4096 and x-r x16 scales
    f32x4 tacc[2][4];

    for (int it = 0; it < 5; ++it) {
        #pragma unroll
        for (int m = 0; m < 2; ++m)
            #pragma unroll
            for (int nt = 0; nt < 4; ++nt)
                tacc[m][nt] = (f32x4){0.f, 0.f, 0.f, 0.f};

        for (int s = 0; s < 24; ++s) {
            const int sn  = (s + 1 == 24) ? 0 : s + 1;
            const int sn2 = (s + 2 >= 24) ? (s + 2 - 24) : s + 2;

            f32x4 d0 = {0,0,0,0}, d1 = {0,0,0,0};
            float dv = 0.f;
            if (it == 0) {
                dv = d0inv[s * 128 + w * 16 + lo];   // exact it0 denom reciprocal
            } else {
                // ---- Phase A: minimal transients (2 ha frags + d0/d1 live)
                #pragma unroll
                for (int c = 0; c < 4; ++c) {
                    frag32 ha0, ha1;
                    const uint4* p0 = reinterpret_cast<const uint4*>(
                        &h8_lds[lo * 528 + c * 128 + hi * 32]);
                    const uint4* p1 = reinterpret_cast<const uint4*>(
                        &h8_lds[(16 + lo) * 528 + c * 128 + hi * 32]);
                    ha0.q[0] = p0[0]; ha0.q[1] = p0[1];
                    ha1.q[0] = p1[0]; ha1.q[1] = p1[1];
                    d0 = MFMA128(ha0.v, w1buf[c].v, d0);
                    d1 = MFMA128(ha1.v, w1buf[c].v, d1);
                }
            }

            // ---- r = x * rcp(denom + eps) -> fp8 in r8_lds  (x pre-scaled x16)
            #pragma unroll
            for (int i = 0; i < 4; ++i) {
                int row0 = hi * 4 + i;
                float x0 = bf2f(x_lds[row0 * 136 + w * 16 + lo]);
                float x1 = bf2f(x_lds[(16 + row0) * 136 + w * 16 + lo]);
                float r0, r1;
                if (it == 0) { r0 = x0 * dv; r1 = x1 * dv; }
                else {
                    r0 = x0 * __builtin_amdgcn_rcpf(fmaf(d0[i], DSCL, 1e-20f));
                    r1 = x1 * __builtin_amdgcn_rcpf(fmaf(d1[i], DSCL, 1e-20f));
                }
                int c0 = __builtin_amdgcn_cvt_pk_fp8_f32(r0, r0, 0, false);
                int c1 = __builtin_amdgcn_cvt_pk_fp8_f32(r1, r1, 0, false);
                r8_lds[row0 * 144 + w * 16 + lo] = (unsigned char)(c0 & 0xff);
                r8_lds[(16 + row0) * 144 + w * 16 + lo] = (unsigned char)(c1 & 0xff);
            }
            LDS_BARRIER();   // barrier A (LDS-only: global prefetches stay in flight)

            // ---- Phase B: r8 frags x w2v (loaded LAST slot); reload w2v[nt]
            //      for slot s+1 immediately after its last use -> ~3000 cy cover
            frag32 ra0, ra1;
            {
                const uint4* p0 = reinterpret_cast<const uint4*>(&r8_lds[lo * 144 + hi * 32]);
                const uint4* p1 = reinterpret_cast<const uint4*>(&r8_lds[(16 + lo) * 144 + hi * 32]);
                ra0.q[0] = p0[0]; ra0.q[1] = p0[1];
                ra1.q[0] = p1[0]; ra1.q[1] = p1[1];
            }
            const unsigned char* w2p = w2base + (size_t)sn * 65536;
            #pragma unroll
            for (int nt = 0; nt < 2; ++nt) {
                tacc[0][nt] = MFMA128(ra0.v, w2v[nt].v, tacc[0][nt]);
                tacc[1][nt] = MFMA128(ra1.v, w2v[nt].v, tacc[1][nt]);
                const uint4* p = reinterpret_cast<const uint4*>(w2p + nt * 2048);
                w2v[nt].q[0] = p[0];
                w2v[nt].q[1] = p[1];
            }

            // ---- reload w1buf = W1[sn] (skip during it0 except last slot)
            if (it > 0 || s == 23) {
                const unsigned char* w1p = w1base + (size_t)sn * 65536;
                #pragma unroll
                for (int c = 0; c < 4; ++c) {
                    const uint4* p = reinterpret_cast<const uint4*>(w1p + c * 2048);
                    w1buf[c].q[0] = p[0];
                    w1buf[c].q[1] = p[1];
                }
            }

            #pragma unroll
            for (int nt = 2; nt < 4; ++nt) {
                tacc[0][nt] = MFMA128(ra0.v, w2v[nt].v, tacc[0][nt]);
                tacc[1][nt] = MFMA128(ra1.v, w2v[nt].v, tacc[1][nt]);
                const uint4* p = reinterpret_cast<const uint4*>(w2p + nt * 2048);
                w2v[nt].q[0] = p[0];
                w2v[nt].q[1] = p[1];
            }

            // ---- stage x[s+1] (loaded last slot), issue x[s+2]
            *reinterpret_cast<uint4*>(xdst) = xnext;
            xnext = xg[(size_t)sn2 * 16];
            LDS_BARRIER();   // barrier B
        }

        // ---- boundary: h_new = normalize(h * (1 + t*2^-16)), fp32 master in LDS
        float hv_[2][4][4];
        float p[2][4];
        #pragma unroll
        for (int m = 0; m < 2; ++m)
            #pragma unroll
            for (int i = 0; i < 4; ++i) p[m][i] = 0.f;

        #pragma unroll
        for (int m = 0; m < 2; ++m)
            #pragma unroll
            for (int nt = 0; nt < 4; ++nt)
                #pragma unroll
                for (int i = 0; i < 4; ++i) {
                    int row = m * 16 + hi * 4 + i;
                    int col = w * 64 + nt * 16 + lo;
                    float hv = h32_lds[row * 516 + col];
                    float v = hv * (1.f + tacc[m][nt][i] * TS);  // EPSILON_0 = 1
                    hv_[m][nt][i] = v;
                    p[m][i] += v;
                }
        #pragma unroll
        for (int mask = 1; mask < 16; mask <<= 1)
            #pragma unroll
            for (int m = 0; m < 2; ++m)
                #pragma unroll
                for (int i = 0; i < 4; ++i)
                    p[m][i] += __shfl_xor(p[m][i], mask, 64);
        if (lo == 0) {
            #pragma unroll
            for (int m = 0; m < 2; ++m)
                #pragma unroll
                for (int i = 0; i < 4; ++i)
                    red[w][m * 16 + hi * 4 + i] = p[m][i];
        }
        __syncthreads();
        float inv[2][4];
        #pragma unroll
        for (int m = 0; m < 2; ++m)
            #pragma unroll
            for (int i = 0; i < 4; ++i) {
                int row = m * 16 + hi * 4 + i;
                float S = 0.f;
                #pragma unroll
                for (int ww = 0; ww < 8; ++ww) S += red[ww][row];
                inv[m][i] = 1.f / (S + 1e-20f);
            }

        if (it < 4) {
            #pragma unroll
            for (int m = 0; m < 2; ++m)
                #pragma unroll
                for (int nt = 0; nt < 4; ++nt)
                    #pragma unroll
                    for (int i = 0; i < 4; ++i) {
                        int row = m * 16 + hi * 4 + i;
                        int col = w * 64 + nt * 16 + lo;
                        float hv = hv_[m][nt][i] * inv[m][i];
                        h32_lds[row * 516 + col] = hv;
                        int c = __builtin_amdgcn_cvt_pk_fp8_f32(hv * 256.0f, hv * 256.0f, 0, false);
                        h8_lds[row * 528 + col] = (unsigned char)(c & 0xff);
                    }
            __syncthreads();
        } else {
            #pragma unroll
            for (int m = 0; m < 2; ++m)
                #pragma unroll
                for (int nt = 0; nt < 4; ++nt)
                    #pragma unroll
                    for (int i = 0; i < 4; ++i) {
                        int row = m * 16 + hi * 4 + i;
                        int col = w * 64 + nt * 16 + lo;
                        out[(size_t)(b0 + row) * 512 + col] = hv_[m][nt][i] * inv[m][i];
                    }
        }
    }
}

extern "C" void kernel_launch(void* const* d_in, const int* in_sizes, int n_in,
                              void* d_out, int out_size, void* d_ws, size_t ws_size,
                              hipStream_t stream) {
    const float* x   = (const float*)d_in[0];   // [8192][3072]
    const float* wgt = (const float*)d_in[1];   // [512][3072]
    const float* h0  = (const float*)d_in[2];   // [512]
    float* out = (float*)d_out;

    // ws: X2 bf16 50,331,648 | W1 fp8 1,572,864 | W2 fp8 1,572,864 | d0inv 12,288
    unsigned short* X2 = (unsigned short*)d_ws;
    unsigned char*  W1 = (unsigned char*)((char*)d_ws + 50331648);
    unsigned char*  W2 = (unsigned char*)((char*)d_ws + 51904512);
    float* d0inv       = (float*)((char*)d_ws + 53477376);

    prep_all<<<8672, 256, 0, stream>>>(x, wgt, h0, X2, W1, W2, d0inv);
    nnmf_main<<<256, 512, 0, stream>>>(X2, W1, W2, d0inv, h0, out);
}

// Round 10
// 402.397 us; speedup vs baseline: 1.0415x; 1.0415x over previous
//
#include <hip/hip_runtime.h>

// NNMF fused: B=8192, NIN=3072, NOUT=512, 5 iterations.
// R16: K=256 super-slots (12/iter) to halve Phase-A h-LDS traffic.
//  R14 pipe audit (per-CU LDS at 128 B/cy): h-frag reads 2048 cy + x 256 +
//  ra 512 + writes 260 + conflicts 537 = ~3640 cy/slot LDS pipe -- the MAX
//  pipe (W-L2 2340, VALU 1140, MFMA 1100) and 76% of the 4812 cy slot. The
//  2048 is the 8x-redundant h-read (every wave reads all of h every slot).
//  R15 lesson (-34us): keep loads at natural region tops; no mid-phase
//  reload tricks. R12 lesson: h-read sharing must not add 32 persistent regs.
//  Fix: slot k-width 256 -> each wave owns 32 kouts (2 tiles); one h-frag
//  read feeds 2 MFMAs -> h traffic and barriers halve, W/MFMA/tacc
//  unchanged. Registers kept flat: W1 streams via rotating 6-frag window
//  (48 regs peak, prefetched 2 c-chunks ahead inside Phase A); W2 khalf0
//  issued at region-1 end (r-conv+barrier cover), khalf1 at region-2 top
//  (8-MFMA cover). Two-barrier rhythm preserved. Numerics identical.

#define NIN 3072
#define NOUT 512

using f32x4 = __attribute__((ext_vector_type(4))) float;
using i32x8 = __attribute__((ext_vector_type(8))) int;

union frag32 { i32x8 v; uint4 q[2]; };

#define MFMA128(A, B, C) \
    __builtin_amdgcn_mfma_scale_f32_16x16x128_f8f6f4( \
        (A), (B), (C), 0, 0, 0, (int)0x7f7f7f7f, 0, (int)0x7f7f7f7f)

__device__ __forceinline__ unsigned short f2bf(float f) {
    unsigned int u = __builtin_bit_cast(unsigned int, f);
    return (unsigned short)((u + 0x7fffu + ((u >> 16) & 1u)) >> 16);  // RNE
}
__device__ __forceinline__ float bf2f(unsigned short s) {
    unsigned int u = ((unsigned int)s) << 16;
    return __builtin_bit_cast(float, u);
}

// LDS-only barrier: cross-wave deps in the slot loop are LDS-only; global
// prefetches stay in flight (consumed by issuing wave, compiler inserts vmcnt).
#define LDS_BARRIER() do {                                   \
    asm volatile("s_waitcnt lgkmcnt(0)" ::: "memory");       \
    __builtin_amdgcn_s_barrier();                            \
    asm volatile("" ::: "memory");                           \
} while (0)

// ---------------------------------------------------------------------------
// prep_all: one launch, 8672 blocks x 256 threads.
//   blocks [0,8192)     : per-row x normalize (x16 pre-scale) -> bf16 X2
//   blocks [8192,8576)  : W -> W2 / W1 (fp8 e4m3, x4096, K=256-slot frag layout)
//   blocks [8576,8672)  : d0inv[k] = 1/(sum_n h0[n]*W[n][k] + 1e-20)
// K=256-slot fragment layouts (12 slots; lane l holds 32 contiguous
// contraction elements, chunk = l>>4):
//   W2 (Phase B B-op): byte = ((((s*8+w)*4+nt)*2+khalf)*64 + l)*32 + j
//     element: n = w*64 + nt*16 + (l&15), k = s*256 + khalf*128 + (l>>4)*32 + j
//   W1 (Phase A B-op): byte = ((((s*8+w)*4+c)*2+kt)*64 + l)*32 + j
//     element: kout = s*256 + w*32 + kt*16 + (l&15), n = c*128 + (l>>4)*32 + j
// ---------------------------------------------------------------------------
__global__ void prep_all(const float* __restrict__ x,
                         const float* __restrict__ W,
                         const float* __restrict__ h_init,
                         unsigned short* __restrict__ X2,
                         unsigned char* __restrict__ W1,
                         unsigned char* __restrict__ W2,
                         float* __restrict__ d0inv) {
    __shared__ float wsum[4];
    __shared__ float dred[8][32];
    const int bb = blockIdx.x;
    const int t  = threadIdx.x;

    if (bb < 8192) {
        // ---- x row normalize -> bf16, pre-scaled x16 (exact: power of 2)
        const int b = bb;
        const float4* r4 = reinterpret_cast<const float4*>(x + (size_t)b * NIN);
        float s = 0.f;
        float4 v0 = r4[t], v1 = r4[t + 256], v2 = r4[t + 512];
        s = v0.x + v0.y + v0.z + v0.w + v1.x + v1.y + v1.z + v1.w + v2.x + v2.y + v2.z + v2.w;
        #pragma unroll
        for (int off = 32; off > 0; off >>= 1) s += __shfl_down(s, off, 64);
        int w = t >> 6, l = t & 63;
        if (l == 0) wsum[w] = s;
        __syncthreads();
        float inv = 16.0f / (wsum[0] + wsum[1] + wsum[2] + wsum[3] + 1e-20f);
        unsigned short* orow = X2 + (size_t)b * NIN;
        #pragma unroll
        for (int c = 0; c < 3; ++c) {
            float4 v = (c == 0) ? v0 : (c == 1) ? v1 : v2;
            ushort4 o;
            o.x = f2bf(v.x * inv); o.y = f2bf(v.y * inv);
            o.z = f2bf(v.z * inv); o.w = f2bf(v.w * inv);
            *reinterpret_cast<ushort4*>(orow + (t + c * 256) * 4) = o;
        }
    } else if (bb < 8192 + 384) {
        // ---- W quantization, K=256-slot frag layouts (32 B per thread)
        int tt = (bb - 8192) * 256 + t;       // 0 .. 98303
        unsigned int words[8];
        if (tt < 49152) {
            // W2: g = ((s*8+w)*4+nt)*2+khalf
            int l = tt & 63, g = tt >> 6;
            int khalf = g & 1, q2 = g >> 1;
            int nt = q2 & 3, q3 = q2 >> 2;
            int w = q3 & 7, s = q3 >> 3;
            int n = w * 64 + nt * 16 + (l & 15);
            int kbase = s * 256 + khalf * 128 + ((l >> 4) << 5);
            const float* src = W + (size_t)n * NIN + kbase;
            #pragma unroll
            for (int q = 0; q < 8; ++q) {
                float v0 = src[q * 4 + 0] * 4096.0f, v1 = src[q * 4 + 1] * 4096.0f;
                float v2 = src[q * 4 + 2] * 4096.0f, v3 = src[q * 4 + 3] * 4096.0f;
                int pk = __builtin_amdgcn_cvt_pk_fp8_f32(v0, v1, 0, false);
                pk     = __builtin_amdgcn_cvt_pk_fp8_f32(v2, v3, pk, true);
                words[q] = (unsigned int)pk;
            }
            uint4* dst = reinterpret_cast<uint4*>(W2 + (size_t)tt * 32);
            dst[0] = *reinterpret_cast<uint4*>(&words[0]);
            dst[1] = *reinterpret_cast<uint4*>(&words[4]);
        } else {
            // W1: g = ((s*8+w)*4+c)*2+kt
            int u = tt - 49152;
            int l = u & 63, g = u >> 6;
            int kt = g & 1, q2 = g >> 1;
            int c = q2 & 3, q3 = q2 >> 2;
            int w = q3 & 7, s = q3 >> 3;
            int kout = s * 256 + w * 32 + kt * 16 + (l & 15);
            int nbase = c * 128 + ((l >> 4) << 5);
            #pragma unroll
            for (int q = 0; q < 8; ++q) {
                float v0 = W[(size_t)(nbase + q * 4 + 0) * NIN + kout] * 4096.0f;
                float v1 = W[(size_t)(nbase + q * 4 + 1) * NIN + kout] * 4096.0f;
                float v2 = W[(size_t)(nbase + q * 4 + 2) * NIN + kout] * 4096.0f;
                float v3 = W[(size_t)(nbase + q * 4 + 3) * NIN + kout] * 4096.0f;
                int pk = __builtin_amdgcn_cvt_pk_fp8_f32(v0, v1, 0, false);
                pk     = __builtin_amdgcn_cvt_pk_fp8_f32(v2, v3, pk, true);
                words[q] = (unsigned int)pk;
            }
            uint4* dst = reinterpret_cast<uint4*>(W1 + (size_t)u * 32);
            dst[0] = *reinterpret_cast<uint4*>(&words[0]);
            dst[1] = *reinterpret_cast<uint4*>(&words[4]);
        }
    } else {
        // ---- d0inv: block owns 32 k-cols; thread (kid = t&31, nsub = t>>5)
        int kb = bb - 8576;                   // 0..95
        int kid = t & 31, nsub = t >> 5;      // 8 n-chunks of 64
        int k = kb * 32 + kid;
        int n0 = nsub * 64;
        float s = 0.f;
        const float* p = W + (size_t)n0 * NIN + k;
        #pragma unroll 8
        for (int n = 0; n < 64; ++n) s += h_init[n0 + n] * p[(size_t)n * NIN];
        dred[nsub][kid] = s;
        __syncthreads();
        if (t < 32) {
            float sm = 1e-20f;
            #pragma unroll
            for (int j = 0; j < 8; ++j) sm += dred[j][t];
            d0inv[kb * 32 + t] = 1.0f / sm;
        }
    }
}

// ---------------------------------------------------------------------------
// Main kernel. 256 blocks x 512 threads (8 waves), 32 rows/block, 1 block/CU.
// 12 K=256 slots; two-barrier rhythm; h master in LDS; MX K=128 fp8 MFMA.
// ---------------------------------------------------------------------------
__global__ __launch_bounds__(512, 1) void nnmf_main(
    const unsigned short* __restrict__ X2,
    const unsigned char* __restrict__ W1,
    const unsigned char* __restrict__ W2,
    const float* __restrict__ d0inv,
    const float* __restrict__ h_init,
    float* __restrict__ out)
{
    __shared__ unsigned char  h8_lds[32 * 528];   // 16.9 KB (fp8 h, x256)
    __shared__ float          h32_lds[32 * 516];  // 66.0 KB (fp32 h master)
    __shared__ unsigned short x_lds[32 * 264];    // 16.9 KB (slot x, stride 264 el)
    __shared__ unsigned char  r8_lds[32 * 272];   //  8.7 KB (fp8 r, stride 272 B)
    __shared__ float red[8][32];
    // total ~110 KB

    const int tid = threadIdx.x;
    const int w  = tid >> 6;        // wave 0..7
    const int l  = tid & 63;
    const int lo = l & 15;
    const int hi = l >> 4;          // 0..3
    const int b0 = blockIdx.x * 32;

    // fp32 h master init (LDS; boundary-only access)
    for (int idx = tid; idx < 32 * 512; idx += 512) {
        int r = idx >> 9, c = idx & 511;
        h32_lds[r * 516 + c] = h_init[c];
    }

    // x staging: thread -> (row, two 16B chunks per slot)
    const int xrow = tid >> 4, xcc = tid & 15;
    const uint4* xgq = reinterpret_cast<const uint4*>(X2 + (size_t)(b0 + xrow) * NIN);
    unsigned short* xdst0 = &x_lds[xrow * 264 + xcc * 8];
    unsigned short* xdst1 = &x_lds[xrow * 264 + 128 + xcc * 8];

    // W pointers (fp8, K=256-slot frag layouts; 32-B aligned per lane)
    const unsigned char* w1base = W1 + (size_t)w * 16384 + (size_t)l * 32;  // +s*131072 +(c*2+kt)*2048
    const unsigned char* w2base = W2 + (size_t)w * 16384 + (size_t)l * 32;  // +s*131072 +(nt*2+khalf)*2048

    // prime pipeline: x slot 0 -> LDS, x slot 1 -> regs
    *reinterpret_cast<uint4*>(xdst0) = xgq[xcc];
    *reinterpret_cast<uint4*>(xdst1) = xgq[xcc + 16];
    uint4 xnA = xgq[32 + xcc], xnB = xgq[32 + xcc + 16];
    frag32 w1w[6];                  // rotating W1 window (valid from it0 s==11 on)
    __syncthreads();

    const float DSCL = 9.5367431640625e-07f;  // 2^-20: undo h x256 * W1 x4096
    const float TS   = 1.0f / 65536.0f;       // undo W2 x4096 and x-r x16 scales
    f32x4 tacc[2][4];

    for (int it = 0; it < 5; ++it) {
        #pragma unroll
        for (int m = 0; m < 2; ++m)
            #pragma unroll
            for (int nt = 0; nt < 4; ++nt)
                tacc[m][nt] = (f32x4){0.f, 0.f, 0.f, 0.f};

        for (int s = 0; s < 12; ++s) {
            const unsigned char* w1s = w1base + (size_t)s * 131072;
            const unsigned char* w2s = w2base + (size_t)s * 131072;

            // =========== region 1: Phase A (K=512 x 32 kouts) + r-conv
            f32x4 d00 = {0,0,0,0}, d01 = {0,0,0,0}, d10 = {0,0,0,0}, d11 = {0,0,0,0};
            float dv0 = 0.f, dv1 = 0.f;
            if (it == 0) {
                dv0 = d0inv[s * 256 + w * 32 + lo];
                dv1 = d0inv[s * 256 + w * 32 + 16 + lo];
            } else {
                frag32 ha0, ha1;
                // ---- c = 0 (w1w[0], w1w[1] preloaded in prior region 2)
                {
                    const uint4* p0 = reinterpret_cast<const uint4*>(&h8_lds[lo * 528 + 0 * 128 + hi * 32]);
                    const uint4* p1 = reinterpret_cast<const uint4*>(&h8_lds[(16 + lo) * 528 + 0 * 128 + hi * 32]);
                    ha0.q[0] = p0[0]; ha0.q[1] = p0[1];
                    ha1.q[0] = p1[0]; ha1.q[1] = p1[1];
                    d00 = MFMA128(ha0.v, w1w[0].v, d00);
                    d01 = MFMA128(ha0.v, w1w[1].v, d01);
                    d10 = MFMA128(ha1.v, w1w[0].v, d10);
                    d11 = MFMA128(ha1.v, w1w[1].v, d11);
                }
                // issue c=2 pair into w1w[4], w1w[5]
                {
                    const uint4* pa = reinterpret_cast<const uint4*>(w1s + 4 * 2048);
                    const uint4* pb = reinterpret_cast<const uint4*>(w1s + 5 * 2048);
                    w1w[4].q[0] = pa[0]; w1w[4].q[1] = pa[1];
                    w1w[5].q[0] = pb[0]; w1w[5].q[1] = pb[1];
                }
                // ---- c = 1 (w1w[2], w1w[3])
                {
                    const uint4* p0 = reinterpret_cast<const uint4*>(&h8_lds[lo * 528 + 1 * 128 + hi * 32]);
                    const uint4* p1 = reinterpret_cast<const uint4*>(&h8_lds[(16 + lo) * 528 + 1 * 128 + hi * 32]);
                    ha0.q[0] = p0[0]; ha0.q[1] = p0[1];
                    ha1.q[0] = p1[0]; ha1.q[1] = p1[1];
                    d00 = MFMA128(ha0.v, w1w[2].v, d00);
                    d01 = MFMA128(ha0.v, w1w[3].v, d01);
                    d10 = MFMA128(ha1.v, w1w[2].v, d10);
                    d11 = MFMA128(ha1.v, w1w[3].v, d11);
                }
                // issue c=3 pair into w1w[0], w1w[1] (dead after c=0)
                {
                    const uint4* pa = reinterpret_cast<const uint4*>(w1s + 6 * 2048);
                    const uint4* pb = reinterpret_cast<const uint4*>(w1s + 7 * 2048);
                    w1w[0].q[0] = pa[0]; w1w[0].q[1] = pa[1];
                    w1w[1].q[0] = pb[0]; w1w[1].q[1] = pb[1];
                }
                // ---- c = 2 (w1w[4], w1w[5])
                {
                    const uint4* p0 = reinterpret_cast<const uint4*>(&h8_lds[lo * 528 + 2 * 128 + hi * 32]);
                    const uint4* p1 = reinterpret_cast<const uint4*>(&h8_lds[(16 + lo) * 528 + 2 * 128 + hi * 32]);
                    ha0.q[0] = p0[0]; ha0.q[1] = p0[1];
                    ha1.q[0] = p1[0]; ha1.q[1] = p1[1];
                    d00 = MFMA128(ha0.v, w1w[4].v, d00);
                    d01 = MFMA128(ha0.v, w1w[5].v, d01);
                    d10 = MFMA128(ha1.v, w1w[4].v, d10);
                    d11 = MFMA128(ha1.v, w1w[5].v, d11);
                }
                // ---- c = 3 (w1w[0], w1w[1])
                {
                    const uint4* p0 = reinterpret_cast<const uint4*>(&h8_lds[lo * 528 + 3 * 128 + hi * 32]);
                    const uint4* p1 = reinterpret_cast<const uint4*>(&h8_lds[(16 + lo) * 528 + 3 * 128 + hi * 32]);
                    ha0.q[0] = p0[0]; ha0.q[1] = p0[1];
                    ha1.q[0] = p1[0]; ha1.q[1] = p1[1];
                    d00 = MFMA128(ha0.v, w1w[0].v, d00);
                    d01 = MFMA128(ha0.v, w1w[1].v, d01);
                    d10 = MFMA128(ha1.v, w1w[0].v, d10);
                    d11 = MFMA128(ha1.v, w1w[1].v, d11);
                }
            }

            // ---- issue W2 khalf0 frags (cover: r-conv + barrier A)
            frag32 w2a[4];
            #pragma unroll
            for (int nt = 0; nt < 4; ++nt) {
                const uint4* p = reinterpret_cast<const uint4*>(w2s + (nt * 2) * 2048);
                w2a[nt].q[0] = p[0];
                w2a[nt].q[1] = p[1];
            }

            // ---- r-conv: r = x * rcp(denom) -> fp8, both kt halves
            #pragma unroll
            for (int kt = 0; kt < 2; ++kt) {
                int col = w * 32 + kt * 16 + lo;
                #pragma unroll
                for (int i = 0; i < 4; ++i) {
                    int row0 = hi * 4 + i;
                    float x0 = bf2f(x_lds[row0 * 264 + col]);
                    float x1 = bf2f(x_lds[(16 + row0) * 264 + col]);
                    float r0, r1;
                    if (it == 0) {
                        float dvv = kt ? dv1 : dv0;
                        r0 = x0 * dvv; r1 = x1 * dvv;
                    } else {
                        float e0 = kt ? d01[i] : d00[i];
                        float e1 = kt ? d11[i] : d10[i];
                        r0 = x0 * __builtin_amdgcn_rcpf(fmaf(e0, DSCL, 1e-20f));
                        r1 = x1 * __builtin_amdgcn_rcpf(fmaf(e1, DSCL, 1e-20f));
                    }
                    int c0 = __builtin_amdgcn_cvt_pk_fp8_f32(r0, r0, 0, false);
                    int c1 = __builtin_amdgcn_cvt_pk_fp8_f32(r1, r1, 0, false);
                    r8_lds[row0 * 272 + col] = (unsigned char)(c0 & 0xff);
                    r8_lds[(16 + row0) * 272 + col] = (unsigned char)(c1 & 0xff);
                }
            }
            LDS_BARRIER();   // barrier A

            // =========== region 2: Phase B (2 khalves) + prefetch
            // ---- issue W2 khalf1 frags (cover: khalf0's 8 MFMAs)
            frag32 w2b[4];
            #pragma unroll
            for (int nt = 0; nt < 4; ++nt) {
                const uint4* p = reinterpret_cast<const uint4*>(w2s + (nt * 2 + 1) * 2048);
                w2b[nt].q[0] = p[0];
                w2b[nt].q[1] = p[1];
            }

            // ---- khalf0 MFMAs
            {
                frag32 ra0, ra1;
                const uint4* p0 = reinterpret_cast<const uint4*>(&r8_lds[lo * 272 + hi * 32]);
                const uint4* p1 = reinterpret_cast<const uint4*>(&r8_lds[(16 + lo) * 272 + hi * 32]);
                ra0.q[0] = p0[0]; ra0.q[1] = p0[1];
                ra1.q[0] = p1[0]; ra1.q[1] = p1[1];
                #pragma unroll
                for (int nt = 0; nt < 4; ++nt) {
                    tacc[0][nt] = MFMA128(ra0.v, w2a[nt].v, tacc[0][nt]);
                    tacc[1][nt] = MFMA128(ra1.v, w2a[nt].v, tacc[1][nt]);
                }
            }

            // ---- preload W1[s+1] c0,c1 pairs into w1w[0..3]
            if (it > 0 || s == 11) {
                int sw = (s == 11) ? 0 : s + 1;
                const unsigned char* w1p = w1base + (size_t)sw * 131072;
                #pragma unroll
                for (int f = 0; f < 4; ++f) {
                    const uint4* p = reinterpret_cast<const uint4*>(w1p + f * 2048);
                    w1w[f].q[0] = p[0];
                    w1w[f].q[1] = p[1];
                }
            }

            // ---- khalf1 MFMAs
            {
                frag32 ra0, ra1;
                const uint4* p0 = reinterpret_cast<const uint4*>(&r8_lds[lo * 272 + 128 + hi * 32]);
                const uint4* p1 = reinterpret_cast<const uint4*>(&r8_lds[(16 + lo) * 272 + 128 + hi * 32]);
                ra0.q[0] = p0[0]; ra0.q[1] = p0[1];
                ra1.q[0] = p1[0]; ra1.q[1] = p1[1];
                #pragma unroll
                for (int nt = 0; nt < 4; ++nt) {
                    tacc[0][nt] = MFMA128(ra0.v, w2b[nt].v, tacc[0][nt]);
                    tacc[1][nt] = MFMA128(ra1.v, w2b[nt].v, tacc[1][nt]);
                }
            }

            // ---- stage x[s+1] (loaded last slot), issue x[s+2]
            *reinterpret_cast<uint4*>(xdst0) = xnA;
            *reinterpret_cast<uint4*>(xdst1) = xnB;
            {
                int f = s + 2; if (f >= 12) f -= 12;
                xnA = xgq[(size_t)f * 32 + xcc];
                xnB = xgq[(size_t)f * 32 + xcc + 16];
            }
            LDS_BARRIER();   // barrier B
        }

        // ---- boundary: h_new = normalize(h * (1 + t*2^-16)), fp32 master in LDS
        float hv_[2][4][4];
        float p[2][4];
        #pragma unroll
        for (int m = 0; m < 2; ++m)
            #pragma unroll
            for (int i = 0; i < 4; ++i) p[m][i] = 0.f;

        #pragma unroll
        for (int m = 0; m < 2; ++m)
            #pragma unroll
            for (int nt = 0; nt < 4; ++nt)
                #pragma unroll
                for (int i = 0; i < 4; ++i) {
                    int row = m * 16 + hi * 4 + i;
                    int col = w * 64 + nt * 16 + lo;
                    float hv = h32_lds[row * 516 + col];
                    float v = hv * (1.f + tacc[m][nt][i] * TS);  // EPSILON_0 = 1
                    hv_[m][nt][i] = v;
                    p[m][i] += v;
                }
        #pragma unroll
        for (int mask = 1; mask < 16; mask <<= 1)
            #pragma unroll
            for (int m = 0; m < 2; ++m)
                #pragma unroll
                for (int i = 0; i < 4; ++i)
                    p[m][i] += __shfl_xor(p[m][i], mask, 64);
        if (lo == 0) {
            #pragma unroll
            for (int m = 0; m < 2; ++m)
                #pragma unroll
                for (int i = 0; i < 4; ++i)
                    red[w][m * 16 + hi * 4 + i] = p[m][i];
        }
        __syncthreads();
        float inv[2][4];
        #pragma unroll
        for (int m = 0; m < 2; ++m)
            #pragma unroll
            for (int i = 0; i < 4; ++i) {
                int row = m * 16 + hi * 4 + i;
                float S = 0.f;
                #pragma unroll
                for (int ww = 0; ww < 8; ++ww) S += red[ww][row];
                inv[m][i] = 1.f / (S + 1e-20f);
            }

        if (it < 4) {
            #pragma unroll
            for (int m = 0; m < 2; ++m)
                #pragma unroll
                for (int nt = 0; nt < 4; ++nt)
                    #pragma unroll
                    for (int i = 0; i < 4; ++i) {
                        int row = m * 16 + hi * 4 + i;
                        int col = w * 64 + nt * 16 + lo;
                        float hv = hv_[m][nt][i] * inv[m][i];
                        h32_lds[row * 516 + col] = hv;
                        int c = __builtin_amdgcn_cvt_pk_fp8_f32(hv * 256.0f, hv * 256.0f, 0, false);
                        h8_lds[row * 528 + col] = (unsigned char)(c & 0xff);
                    }
            __syncthreads();
        } else {
            #pragma unroll
            for (int m = 0; m < 2; ++m)
                #pragma unroll
                for (int nt = 0; nt < 4; ++nt)
                    #pragma unroll
                    for (int i = 0; i < 4; ++i) {
                        int row = m * 16 + hi * 4 + i;
                        int col = w * 64 + nt * 16 + lo;
                        out[(size_t)(b0 + row) * 512 + col] = hv_[m][nt][i] * inv[m][i];
                    }
        }
    }
}

extern "C" void kernel_launch(void* const* d_in, const int* in_sizes, int n_in,
                              void* d_out, int out_size, void* d_ws, size_t ws_size,
                              hipStream_t stream) {
    const float* x   = (const float*)d_in[0];   // [8192][3072]
    const float* wgt = (const float*)d_in[1];   // [512][3072]
    const float* h0  = (const float*)d_in[2];   // [512]
    float* out = (float*)d_out;

    // ws: X2 bf16 50,331,648 | W1 fp8 1,572,864 | W2 fp8 1,572,864 | d0inv 12,288
    unsigned short* X2 = (unsigned short*)d_ws;
    unsigned char*  W1 = (unsigned char*)((char*)d_ws + 50331648);
    unsigned char*  W2 = (unsigned char*)((char*)d_ws + 51904512);
    float* d0inv       = (float*)((char*)d_ws + 53477376);

    prep_all<<<8672, 256, 0, stream>>>(x, wgt, h0, X2, W1, W2, d0inv);
    nnmf_main<<<256, 512, 0, stream>>>(X2, W1, W2, d0inv, h0, out);
}

// Round 12
// 381.293 us; speedup vs baseline: 1.0991x; 1.0553x over previous
//
#include <hip/hip_runtime.h>

// NNMF fused: B=8192, NIN=3072, NOUT=512, 5 iterations.
// R18: R14 structure + W1-only fp6 (hybrid precision).
//  R17 (fp6 both) FAILED absmax 1.9e-4: error propagation says Phase-B (W2)
//  dominates -- its per-element quantization error enters t as a sqrt(3072)-
//  term random sum with O(1) weights (~2e-4), while Phase-A (W1) error is
//  damped ~50x (enters denom, divided, re-averaged over 3072 k). So: W1 fp6
//  e2m3 x2^13 (24B frags, MFMA f8f6f4 blgp=2), W2 stays fp8 e4m3 x4096
//  (exact R14 path). W stream 128->112 KB/slot (-12.5%); w1buf 32->24 VGPR.
//  DSCL = 2^-21 (h x2^8 * W1 x2^13), TS = 2^-16 (r x2^4 * W2 x2^12).
//  Everything else byte-identical to R14 (best measured, 240.6 us).

#define NIN 3072
#define NOUT 512

using f32x4 = __attribute__((ext_vector_type(4))) float;
using i32x8 = __attribute__((ext_vector_type(8))) int;

union frag32 { i32x8 v; uint4 q[2]; };

// A = fp8 e4m3, B = fp8 e4m3, scales = 2^0
#define MFMA128(A, B, C) \
    __builtin_amdgcn_mfma_scale_f32_16x16x128_f8f6f4( \
        (A), (B), (C), 0, 0, 0, (int)0x7f7f7f7f, 0, (int)0x7f7f7f7f)
// A = fp8 e4m3 (cbsz=0), B = fp6 e2m3 (blgp=2), scales = 2^0
#define MFMA128_F6(A, B, C) \
    __builtin_amdgcn_mfma_scale_f32_16x16x128_f8f6f4( \
        (A), (B), (C), 0, 2, 0, (int)0x7f7f7f7f, 0, (int)0x7f7f7f7f)

__device__ __forceinline__ unsigned short f2bf(float f) {
    unsigned int u = __builtin_bit_cast(unsigned int, f);
    return (unsigned short)((u + 0x7fffu + ((u >> 16) & 1u)) >> 16);  // RNE
}
__device__ __forceinline__ float bf2f(unsigned short s) {
    unsigned int u = ((unsigned int)s) << 16;
    return __builtin_bit_cast(float, u);
}

// e2m3 encode of nonnegative p (caller guarantees p <= 7.75)
__device__ __forceinline__ unsigned enc_fp6(float p) {
    if (p < 1.9375f) {                 // denormal + e=1: step 0.125, codes 0..15
        int q = (int)rintf(p * 8.0f);
        return (unsigned)q;
    }
    if (p < 3.875f) {                  // e=2: step 0.25, codes 16..23
        int m = (int)rintf((p - 2.0f) * 4.0f);
        return (m > 7) ? 24u : (16u + (unsigned)m);
    }
    int m = (int)rintf((p - 4.0f) * 2.0f);  // e=3: step 0.5, codes 24..31
    if (m > 7) m = 7;
    return 24u + (unsigned)m;
}

// load a 24-byte fp6 fragment (8B-aligned) into the low 6 dwords
__device__ __forceinline__ void load6(frag32& f, const unsigned char* p) {
    const uint2* q = reinterpret_cast<const uint2*>(p);
    uint2 a = q[0], b = q[1], c = q[2];
    f.v = (i32x8){(int)a.x, (int)a.y, (int)b.x, (int)b.y, (int)c.x, (int)c.y, 0, 0};
}

// LDS-only barrier: cross-wave deps in the slot loop are LDS-only; global
// prefetches stay in flight (consumed by issuing wave, compiler inserts vmcnt).
#define LDS_BARRIER() do {                                   \
    asm volatile("s_waitcnt lgkmcnt(0)" ::: "memory");       \
    __builtin_amdgcn_s_barrier();                            \
    asm volatile("" ::: "memory");                           \
} while (0)

// ---------------------------------------------------------------------------
// prep_all: one launch, 8672 blocks x 256 threads.
//   blocks [0,8192)     : per-row x normalize (x16 pre-scale) -> bf16 X2
//   blocks [8192,8576)  : W -> W2 (fp8 x4096) / W1 (fp6 e2m3 x8192)
//   blocks [8576,8672)  : d0inv[k] = 1/(sum_n h0[n]*W[n][k] + 1e-20)  (exact fp32)
// K=128 fragment layouts (lane l holds 32 contiguous contraction elements,
// k = (l>>4)*32 + j):
//   W2 (Phase B B-op, fp8 32B): byte = ((s*32 + w*4 + nt)*64 + l)*32 + j
//     element: n = w*64 + nt*16 + (l&15), k = s*128 + (l>>4)*32 + j
//   W1 (Phase A B-op, fp6 24B): frag = ((s*8 + w)*4 + c)*64 + l, byte = frag*24,
//     element j at bits [6j+5:6j]: kout = s*128 + w*16 + (l&15), n = c*128 + (l>>4)*32 + j
// ---------------------------------------------------------------------------
__global__ void prep_all(const float* __restrict__ x,
                         const float* __restrict__ W,
                         const float* __restrict__ h_init,
                         unsigned short* __restrict__ X2,
                         unsigned char* __restrict__ W1,
                         unsigned char* __restrict__ W2,
                         float* __restrict__ d0inv) {
    __shared__ float wsum[4];
    __shared__ float dred[8][32];
    const int bb = blockIdx.x;
    const int t  = threadIdx.x;

    if (bb < 8192) {
        // ---- x row normalize -> bf16, pre-scaled x16 (exact: power of 2)
        const int b = bb;
        const float4* r4 = reinterpret_cast<const float4*>(x + (size_t)b * NIN);
        float s = 0.f;
        float4 v0 = r4[t], v1 = r4[t + 256], v2 = r4[t + 512];
        s = v0.x + v0.y + v0.z + v0.w + v1.x + v1.y + v1.z + v1.w + v2.x + v2.y + v2.z + v2.w;
        #pragma unroll
        for (int off = 32; off > 0; off >>= 1) s += __shfl_down(s, off, 64);
        int w = t >> 6, l = t & 63;
        if (l == 0) wsum[w] = s;
        __syncthreads();
        float inv = 16.0f / (wsum[0] + wsum[1] + wsum[2] + wsum[3] + 1e-20f);
        unsigned short* orow = X2 + (size_t)b * NIN;
        #pragma unroll
        for (int c = 0; c < 3; ++c) {
            float4 v = (c == 0) ? v0 : (c == 1) ? v1 : v2;
            ushort4 o;
            o.x = f2bf(v.x * inv); o.y = f2bf(v.y * inv);
            o.z = f2bf(v.z * inv); o.w = f2bf(v.w * inv);
            *reinterpret_cast<ushort4*>(orow + (t + c * 256) * 4) = o;
        }
    } else if (bb < 8192 + 384) {
        int tt = (bb - 8192) * 256 + t;       // 0 .. 98303
        if (tt < 49152) {
            // ---- W2 fp8 x4096 (exact R14 path)
            int l = tt & 63, g = tt >> 6;
            int s = g >> 5, rem = g & 31, w = rem >> 2, nt = rem & 3;
            int n = w * 64 + nt * 16 + (l & 15);
            int kbase = s * 128 + ((l >> 4) << 5);
            const float* src = W + (size_t)n * NIN + kbase;
            unsigned int words[8];
            #pragma unroll
            for (int q = 0; q < 8; ++q) {
                float v0 = src[q * 4 + 0] * 4096.0f, v1 = src[q * 4 + 1] * 4096.0f;
                float v2 = src[q * 4 + 2] * 4096.0f, v3 = src[q * 4 + 3] * 4096.0f;
                int pk = __builtin_amdgcn_cvt_pk_fp8_f32(v0, v1, 0, false);
                pk     = __builtin_amdgcn_cvt_pk_fp8_f32(v2, v3, pk, true);
                words[q] = (unsigned int)pk;
            }
            uint4* dst = reinterpret_cast<uint4*>(W2 + (size_t)tt * 32);
            dst[0] = *reinterpret_cast<uint4*>(&words[0]);
            dst[1] = *reinterpret_cast<uint4*>(&words[4]);
        } else {
            // ---- W1 fp6 e2m3 x8192 (24 B per fragment)
            int u = tt - 49152;
            int l = u & 63, g = u >> 6;
            int c = g & 3, sw = g >> 2;
            int w = sw & 7, s = sw >> 3;
            int kout = s * 128 + w * 16 + (l & 15);
            int nbase = c * 128 + ((l >> 4) << 5);
            float v[32];
            #pragma unroll
            for (int j = 0; j < 32; ++j)
                v[j] = W[(size_t)(nbase + j) * NIN + kout] * 8192.0f;
            unsigned int dw[6] = {0, 0, 0, 0, 0, 0};
            #pragma unroll
            for (int j = 0; j < 32; ++j) {
                unsigned c6 = enc_fp6(v[j]);
                int bit = 6 * j, di = bit >> 5, off = bit & 31;
                dw[di] |= c6 << off;
                if (off > 26) dw[di + 1] |= c6 >> (32 - off);
            }
            uint2* d2 = reinterpret_cast<uint2*>(W1 + (size_t)u * 24);
            d2[0] = make_uint2(dw[0], dw[1]);
            d2[1] = make_uint2(dw[2], dw[3]);
            d2[2] = make_uint2(dw[4], dw[5]);
        }
    } else {
        // ---- d0inv: block owns 32 k-cols; thread (kid = t&31, nsub = t>>5)
        int kb = bb - 8576;                   // 0..95
        int kid = t & 31, nsub = t >> 5;      // 8 n-chunks of 64
        int k = kb * 32 + kid;
        int n0 = nsub * 64;
        float s = 0.f;
        const float* p = W + (size_t)n0 * NIN + k;
        #pragma unroll 8
        for (int n = 0; n < 64; ++n) s += h_init[n0 + n] * p[(size_t)n * NIN];
        dred[nsub][kid] = s;
        __syncthreads();
        if (t < 32) {
            float sm = 1e-20f;
            #pragma unroll
            for (int j = 0; j < 8; ++j) sm += dred[j][t];
            d0inv[kb * 32 + t] = 1.0f / sm;
        }
    }
}

// ---------------------------------------------------------------------------
// Main kernel. 256 blocks x 512 threads (8 waves), 32 rows/block, 1 block/CU.
// R14 two-barrier slot structure; h master in LDS; Phase A fp8xfp6, Phase B fp8.
// ---------------------------------------------------------------------------
__global__ __launch_bounds__(512, 1) void nnmf_main(
    const unsigned short* __restrict__ X2,
    const unsigned char* __restrict__ W1,
    const unsigned char* __restrict__ W2,
    const float* __restrict__ d0inv,
    const float* __restrict__ h_init,
    float* __restrict__ out)
{
    __shared__ unsigned char  h8_lds[32 * 528];   // 16.9 KB (fp8 h, x256)
    __shared__ float          h32_lds[32 * 516];  // 66.0 KB (fp32 h master)
    __shared__ unsigned short x_lds[32 * 136];    //  8.7 KB
    __shared__ unsigned char  r8_lds[32 * 144];   //  4.6 KB (fp8 r, stride 144B)
    __shared__ float red[8][32];
    // total ~97.3 KB

    const int tid = threadIdx.x;
    const int w  = tid >> 6;        // wave 0..7
    const int l  = tid & 63;
    const int lo = l & 15;
    const int hi = l >> 4;          // 0..3
    const int b0 = blockIdx.x * 32;

    // fp32 h master init (LDS; each (row,col) owned by one thread at boundary)
    for (int idx = tid; idx < 32 * 512; idx += 512) {
        int r = idx >> 9, c = idx & 511;
        h32_lds[r * 516 + c] = h_init[c];
    }

    // x staging: thread -> (row, 16B chunk)
    const int xrow = tid >> 4, xcc = tid & 15;
    const uint4* xg = reinterpret_cast<const uint4*>(X2 + (size_t)(b0 + xrow) * NIN + xcc * 8);
    unsigned short* xdst = &x_lds[xrow * 136 + xcc * 8];

    // W pointers
    const unsigned char* w1base = W1 + ((size_t)(w * 4) * 64 + l) * 24;  // +s*49152 +c*1536 (fp6)
    const unsigned char* w2base = W2 + (size_t)w * 8192 + (size_t)l * 32; // +s*65536 +nt*2048 (fp8)

    // prime pipeline: x[0] -> LDS, x[1] -> reg
    *reinterpret_cast<uint4*>(xdst) = xg[0];
    uint4 xnext = xg[16];
    frag32 w1buf[4];                // Phase A B-frags fp6 (valid from it0 s==23 on)
    __syncthreads();

    const float DSCL = 4.76837158203125e-07f;  // 2^-21: undo h x2^8 * W1 x2^13
    const float TS   = 1.0f / 65536.0f;        // 2^-16: undo W2 x2^12 and x-r x2^4
    f32x4 tacc[2][4];

    for (int it = 0; it < 5; ++it) {
        #pragma unroll
        for (int m = 0; m < 2; ++m)
            #pragma unroll
            for (int nt = 0; nt < 4; ++nt)
                tacc[m][nt] = (f32x4){0.f, 0.f, 0.f, 0.f};

        for (int s = 0; s < 24; ++s) {
            const int sn  = (s + 1 == 24) ? 0 : s + 1;
            const int sn2 = (s + 2 >= 24) ? (s + 2 - 24) : s + 2;

            // ---- issue W2[s] loads (4 x 32B fp8 frags; consumed after barrier A)
            frag32 w2v[4];
            {
                const unsigned char* w2p = w2base + (size_t)s * 65536;
                #pragma unroll
                for (int nt = 0; nt < 4; ++nt) {
                    const uint4* p = reinterpret_cast<const uint4*>(w2p + nt * 2048);
                    w2v[nt].q[0] = p[0];
                    w2v[nt].q[1] = p[1];
                }
            }

            f32x4 d0 = {0,0,0,0}, d1 = {0,0,0,0};
            float dv = 0.f;
            if (it == 0) {
                dv = d0inv[s * 128 + w * 16 + lo];   // exact it0 denom reciprocal
            } else {
                // ---- Phase A: h fp8 (A) x W1 fp6 (B), minimal transients
                #pragma unroll
                for (int c = 0; c < 4; ++c) {
                    frag32 ha0, ha1;
                    const uint4* p0 = reinterpret_cast<const uint4*>(
                        &h8_lds[lo * 528 + c * 128 + hi * 32]);
                    const uint4* p1 = reinterpret_cast<const uint4*>(
                        &h8_lds[(16 + lo) * 528 + c * 128 + hi * 32]);
                    ha0.q[0] = p0[0]; ha0.q[1] = p0[1];
                    ha1.q[0] = p1[0]; ha1.q[1] = p1[1];
                    d0 = MFMA128_F6(ha0.v, w1buf[c].v, d0);
                    d1 = MFMA128_F6(ha1.v, w1buf[c].v, d1);
                }
            }

            // ---- r = x * rcp(denom + eps) -> fp8 in r8_lds  (x pre-scaled x16)
            #pragma unroll
            for (int i = 0; i < 4; ++i) {
                int row0 = hi * 4 + i;
                float x0 = bf2f(x_lds[row0 * 136 + w * 16 + lo]);
                float x1 = bf2f(x_lds[(16 + row0) * 136 + w * 16 + lo]);
                float r0, r1;
                if (it == 0) { r0 = x0 * dv; r1 = x1 * dv; }
                else {
                    r0 = x0 * __builtin_amdgcn_rcpf(fmaf(d0[i], DSCL, 1e-20f));
                    r1 = x1 * __builtin_amdgcn_rcpf(fmaf(d1[i], DSCL, 1e-20f));
                }
                int c0 = __builtin_amdgcn_cvt_pk_fp8_f32(r0, r0, 0, false);
                int c1 = __builtin_amdgcn_cvt_pk_fp8_f32(r1, r1, 0, false);
                r8_lds[row0 * 144 + w * 16 + lo] = (unsigned char)(c0 & 0xff);
                r8_lds[(16 + row0) * 144 + w * 16 + lo] = (unsigned char)(c1 & 0xff);
            }
            LDS_BARRIER();   // barrier A (LDS-only: global prefetches stay in flight)

            // ---- Phase B: r8 frags (fp8) x w2v (fp8)
            frag32 ra0, ra1;
            {
                const uint4* p0 = reinterpret_cast<const uint4*>(&r8_lds[lo * 144 + hi * 32]);
                const uint4* p1 = reinterpret_cast<const uint4*>(&r8_lds[(16 + lo) * 144 + hi * 32]);
                ra0.q[0] = p0[0]; ra0.q[1] = p0[1];
                ra1.q[0] = p1[0]; ra1.q[1] = p1[1];
            }
            #pragma unroll
            for (int nt = 0; nt < 2; ++nt) {
                tacc[0][nt] = MFMA128(ra0.v, w2v[nt].v, tacc[0][nt]);
                tacc[1][nt] = MFMA128(ra1.v, w2v[nt].v, tacc[1][nt]);
            }

            // ---- reload w1buf = W1[sn] fp6 (skip during it0 except last slot)
            if (it > 0 || s == 23) {
                const unsigned char* w1p = w1base + (size_t)sn * 49152;
                #pragma unroll
                for (int c = 0; c < 4; ++c)
                    load6(w1buf[c], w1p + c * 1536);
            }

            #pragma unroll
            for (int nt = 2; nt < 4; ++nt) {
                tacc[0][nt] = MFMA128(ra0.v, w2v[nt].v, tacc[0][nt]);
                tacc[1][nt] = MFMA128(ra1.v, w2v[nt].v, tacc[1][nt]);
            }

            // ---- stage x[s+1] (loaded last slot), issue x[s+2]
            *reinterpret_cast<uint4*>(xdst) = xnext;
            xnext = xg[(size_t)sn2 * 16];
            LDS_BARRIER();   // barrier B
        }

        // ---- boundary: h_new = normalize(h * (1 + t*2^-16)), fp32 master in LDS
        float hv_[2][4][4];
        float p[2][4];
        #pragma unroll
        for (int m = 0; m < 2; ++m)
            #pragma unroll
            for (int i = 0; i < 4; ++i) p[m][i] = 0.f;

        #pragma unroll
        for (int m = 0; m < 2; ++m)
            #pragma unroll
            for (int nt = 0; nt < 4; ++nt)
                #pragma unroll
                for (int i = 0; i < 4; ++i) {
                    int row = m * 16 + hi * 4 + i;
                    int col = w * 64 + nt * 16 + lo;
                    float hv = h32_lds[row * 516 + col];
                    float v = hv * (1.f + tacc[m][nt][i] * TS);  // EPSILON_0 = 1
                    hv_[m][nt][i] = v;
                    p[m][i] += v;
                }
        #pragma unroll
        for (int mask = 1; mask < 16; mask <<= 1)
            #pragma unroll
            for (int m = 0; m < 2; ++m)
                #pragma unroll
                for (int i = 0; i < 4; ++i)
                    p[m][i] += __shfl_xor(p[m][i], mask, 64);
        if (lo == 0) {
            #pragma unroll
            for (int m = 0; m < 2; ++m)
                #pragma unroll
                for (int i = 0; i < 4; ++i)
                    red[w][m * 16 + hi * 4 + i] = p[m][i];
        }
        __syncthreads();
        float inv[2][4];
        #pragma unroll
        for (int m = 0; m < 2; ++m)
            #pragma unroll
            for (int i = 0; i < 4; ++i) {
                int row = m * 16 + hi * 4 + i;
                float S = 0.f;
                #pragma unroll
                for (int ww = 0; ww < 8; ++ww) S += red[ww][row];
                inv[m][i] = 1.f / (S + 1e-20f);
            }

        if (it < 4) {
            #pragma unroll
            for (int m = 0; m < 2; ++m)
                #pragma unroll
                for (int nt = 0; nt < 4; ++nt)
                    #pragma unroll
                    for (int i = 0; i < 4; ++i) {
                        int row = m * 16 + hi * 4 + i;
                        int col = w * 64 + nt * 16 + lo;
                        float hv = hv_[m][nt][i] * inv[m][i];
                        h32_lds[row * 516 + col] = hv;
                        int c = __builtin_amdgcn_cvt_pk_fp8_f32(hv * 256.0f, hv * 256.0f, 0, false);
                        h8_lds[row * 528 + col] = (unsigned char)(c & 0xff);
                    }
            __syncthreads();
        } else {
            #pragma unroll
            for (int m = 0; m < 2; ++m)
                #pragma unroll
                for (int nt = 0; nt < 4; ++nt)
                    #pragma unroll
                    for (int i = 0; i < 4; ++i) {
                        int row = m * 16 + hi * 4 + i;
                        int col = w * 64 + nt * 16 + lo;
                        out[(size_t)(b0 + row) * 512 + col] = hv_[m][nt][i] * inv[m][i];
                    }
        }
    }
}

extern "C" void kernel_launch(void* const* d_in, const int* in_sizes, int n_in,
                              void* d_out, int out_size, void* d_ws, size_t ws_size,
                              hipStream_t stream) {
    const float* x   = (const float*)d_in[0];   // [8192][3072]
    const float* wgt = (const float*)d_in[1];   // [512][3072]
    const float* h0  = (const float*)d_in[2];   // [512]
    float* out = (float*)d_out;

    // ws: X2 bf16 50,331,648 | W1 fp6 1,179,648 | W2 fp8 1,572,864 | d0inv 12,288
    unsigned short* X2 = (unsigned short*)d_ws;
    unsigned char*  W1 = (unsigned char*)((char*)d_ws + 50331648);
    unsigned char*  W2 = (unsigned char*)((char*)d_ws + 51511296);
    float* d0inv       = (float*)((char*)d_ws + 53084160);

    prep_all<<<8672, 256, 0, stream>>>(x, wgt, h0, X2, W1, W2, d0inv);
    nnmf_main<<<256, 512, 0, stream>>>(X2, W1, W2, d0inv, h0, out);
}